// Round 3
// baseline (695.023 us; speedup 1.0000x reference)
//
#include <hip/hip_runtime.h>
#include <hip/hip_bf16.h>
#include <stdint.h>

#define B_  4
#define S_  2048
#define D_  1024
#define H_  16
#define DK_ 64
#define M_  (B_*S_)   // 8192

typedef unsigned short u16;
using bh8  = __attribute__((ext_vector_type(8))) short;
using fx4  = __attribute__((ext_vector_type(4))) float;

__device__ __forceinline__ u16 f2bf(float f){
  union { float f; uint32_t u; } v; v.f = f;
  uint32_t r = v.u + 0x7FFFu + ((v.u >> 16) & 1u);
  return (u16)(r >> 16);
}

// ---------- transpose+convert 1024x1024: out_bf16[n][k] = in_f32[k][n] ----------
__global__ __launch_bounds__(256) void transpose_k(const float* __restrict__ in,
                                                   u16* __restrict__ out){
  __shared__ u16 tile[32][33];
  int tx = threadIdx.x, ty = threadIdx.y;
  int x0 = blockIdx.x*32, y0 = blockIdx.y*32;
  #pragma unroll
  for (int j=0;j<32;j+=8) tile[ty+j][tx] = f2bf(in[(size_t)(y0+ty+j)*D_ + x0+tx]);
  __syncthreads();
  #pragma unroll
  for (int j=0;j<32;j+=8) out[(size_t)(x0+ty+j)*D_ + y0+tx] = tile[tx][ty+j];
}

// ---------- C[M,N] = A[M,K] @ BT[N,K]^T, fp32 accum ----------
// A fp32 (AF32, converted in staging) or bf16. BT bf16. C fp32 (COUT32) or bf16.
// 128x128 tile / block, 4 waves, each wave 64x64 via 4x4 mfma_f32_16x16x32_bf16.
// LDS slot layout: slot = kc*128 + r (16B slots).
template<bool AF32, bool COUT32>
__global__ __launch_bounds__(256) void gemm_bt(const void* __restrict__ Aptr,
                                               const u16* __restrict__ BT,
                                               void* __restrict__ Cptr,
                                               int Kdim, int Ndim){
  __shared__ __align__(16) u16 Asl[128*32];
  __shared__ __align__(16) u16 Bsl[128*32];
  int tid  = threadIdx.x;
  int w    = tid >> 6, lane = tid & 63, quad = lane >> 4, ln = lane & 15;
  int waveM = w >> 1, waveN = w & 1;
  int rowBase = blockIdx.y*128, colBase = blockIdx.x*128;

  fx4 acc[4][4];
  #pragma unroll
  for (int i=0;i<4;i++)
    #pragma unroll
    for (int j=0;j<4;j++) acc[i][j] = (fx4){0.f,0.f,0.f,0.f};

  for (int k0 = 0; k0 < Kdim; k0 += 32){
    __syncthreads();
    #pragma unroll
    for (int i=0;i<2;i++){
      int slot = i*256 + tid;
      int kc = slot >> 7, r = slot & 127;
      if (AF32){
        const float* A = (const float*)Aptr;
        const float4* src = (const float4*)&A[(size_t)(rowBase + r)*Kdim + k0 + kc*8];
        float4 a0 = src[0], a1 = src[1];
        u16* dst = &Asl[slot*8];
        dst[0]=f2bf(a0.x); dst[1]=f2bf(a0.y); dst[2]=f2bf(a0.z); dst[3]=f2bf(a0.w);
        dst[4]=f2bf(a1.x); dst[5]=f2bf(a1.y); dst[6]=f2bf(a1.z); dst[7]=f2bf(a1.w);
      } else {
        const u16* A = (const u16*)Aptr;
        *(bh8*)(&Asl[slot*8]) = *(const bh8*)(&A[(size_t)(rowBase + r)*Kdim + k0 + kc*8]);
      }
      *(bh8*)(&Bsl[slot*8]) = *(const bh8*)(&BT[(size_t)(colBase + r)*Kdim + k0 + kc*8]);
    }
    __syncthreads();
    bh8 af[4], bf[4];
    #pragma unroll
    for (int t=0;t<4;t++){
      af[t] = *(const bh8*)(&Asl[(quad*128 + waveM*64 + t*16 + ln)*8]);
      bf[t] = *(const bh8*)(&Bsl[(quad*128 + waveN*64 + t*16 + ln)*8]);
    }
    #pragma unroll
    for (int i=0;i<4;i++)
      #pragma unroll
      for (int j=0;j<4;j++)
        acc[i][j] = __builtin_amdgcn_mfma_f32_16x16x32_bf16(af[i], bf[j], acc[i][j], 0, 0, 0);
  }

  // epilogue: C/D layout col = lane&15, row = quad*4 + reg  [m89/m91-verified]
  #pragma unroll
  for (int i=0;i<4;i++){
    int row0 = rowBase + waveM*64 + i*16 + quad*4;
    #pragma unroll
    for (int j=0;j<4;j++){
      int col = colBase + waveN*64 + j*16 + ln;
      #pragma unroll
      for (int r=0;r<4;r++){
        if (COUT32) ((float*)Cptr)[(size_t)(row0 + r)*Ndim + col] = acc[i][j][r];
        else        ((u16*)  Cptr)[(size_t)(row0 + r)*Ndim + col] = f2bf(acc[i][j][r]);
      }
    }
  }
}

// ---------- flash attention, causal, one block per (b,h, 64-row q tile) ----------
// NOTE: O aliases Q (same buffer). Safe: each block reads exactly the Q region
// it later writes (into registers, before its first store); all other blocks
// touch disjoint (row, head-col) regions of the buffer.
__global__ __launch_bounds__(256) void attn_k(const u16* __restrict__ Q,
                                              const u16* __restrict__ Kp,
                                              const u16* __restrict__ Vp,
                                              u16* __restrict__ O){
  __shared__ __align__(16) u16 Kt[64*64];     // slot = kc*64 + n   (kc = dk/8)
  __shared__ __align__(16) u16 Vt[64*64];     // slot = pc*64 + vd  (pc = kpos/8), transposed
  __shared__ __align__(16) u16 Pb[4*16*64];   // per-wave P, slot = pc*16 + m

  int qt = blockIdx.x;
  int b  = blockIdx.y >> 4, h = blockIdx.y & 15;
  int tid = threadIdx.x;
  int w = tid >> 6, lane = tid & 63, quad = lane >> 4, ln = lane & 15;
  int q0w = qt*64 + w*16;
  size_t headoff = (size_t)h*DK_;

  // Q fragments (A-operand: m=lane&15, k=quad*8+j), held in regs for whole loop
  bh8 qf0, qf1;
  {
    const u16* qp = Q + (size_t)(b*S_ + q0w + ln)*D_ + headoff + quad*8;
    qf0 = *(const bh8*)qp;
    qf1 = *(const bh8*)(qp + 32);
  }

  float m_i[4], l_i[4];
  fx4 oacc[4];
  #pragma unroll
  for (int r=0;r<4;r++){ m_i[r] = -1e30f; l_i[r] = 0.f; }
  #pragma unroll
  for (int t=0;t<4;t++) oacc[t] = (fx4){0.f,0.f,0.f,0.f};

  u16* Pw = &Pb[w*16*64];
  int ntiles = qt + 1;                        // causal: skip tiles with k0 > q_max
  for (int kt=0; kt<ntiles; kt++){
    int k0 = kt*64;
    __syncthreads();
    // stage K (B-operand friendly): slot kc*64+n holds K[k0+n][dk = kc*8 .. +8]
    #pragma unroll
    for (int i=0;i<2;i++){
      int slot = i*256 + tid;
      int kc = slot >> 6, n = slot & 63;
      *(bh8*)(&Kt[slot*8]) = *(const bh8*)(&Kp[(size_t)(b*S_ + k0 + n)*D_ + headoff + kc*8]);
    }
    // stage V transposed: Vt[pc*64+vd] slot, position kpos&7
    #pragma unroll
    for (int i=0;i<2;i++){
      int c = i*256 + tid;
      int kpos = c >> 3, vc = c & 7;
      bh8 vv = *(const bh8*)(&Vp[(size_t)(b*S_ + k0 + kpos)*D_ + headoff + vc*8]);
      int pc = kpos >> 3, jj = kpos & 7;
      #pragma unroll
      for (int e=0;e<8;e++)
        Vt[(pc*64 + vc*8 + e)*8 + jj] = (u16)vv[e];
    }
    __syncthreads();

    // scores: S[16q x 64k] per wave = 4 accs, 2 dk-steps each
    fx4 sacc[4];
    #pragma unroll
    for (int t=0;t<4;t++){
      bh8 kf0 = *(const bh8*)(&Kt[((0*4+quad)*64 + t*16 + ln)*8]);
      bh8 kf1 = *(const bh8*)(&Kt[((1*4+quad)*64 + t*16 + ln)*8]);
      fx4 z = (fx4){0.f,0.f,0.f,0.f};
      z = __builtin_amdgcn_mfma_f32_16x16x32_bf16(qf0, kf0, z, 0,0,0);
      z = __builtin_amdgcn_mfma_f32_16x16x32_bf16(qf1, kf1, z, 0,0,0);
      sacc[t] = z;
    }

    // scale + causal mask; online softmax (rows = quad*4+reg, cols = lane&15)
    float rowmax[4] = {-1e30f,-1e30f,-1e30f,-1e30f};
    #pragma unroll
    for (int t=0;t<4;t++){
      int kg = k0 + t*16 + ln;
      #pragma unroll
      for (int r=0;r<4;r++){
        int qg = q0w + quad*4 + r;
        float sv = sacc[t][r]*0.125f;            // 1/sqrt(64)
        sv = (kg <= qg) ? sv : -1e30f;
        sacc[t][r] = sv;
        rowmax[r] = fmaxf(rowmax[r], sv);
      }
    }
    #pragma unroll
    for (int r=0;r<4;r++)
      #pragma unroll
      for (int off=1; off<16; off<<=1)
        rowmax[r] = fmaxf(rowmax[r], __shfl_xor(rowmax[r], off, 64));

    float alpha[4], rowsum[4];
    #pragma unroll
    for (int r=0;r<4;r++){
      float mn = fmaxf(m_i[r], rowmax[r]);
      alpha[r] = __expf(m_i[r] - mn);
      m_i[r] = mn;
      rowsum[r] = 0.f;
    }
    #pragma unroll
    for (int t=0;t<4;t++)
      #pragma unroll
      for (int r=0;r<4;r++){
        float p = __expf(sacc[t][r] - m_i[r]);
        sacc[t][r] = p;
        rowsum[r] += p;
      }
    #pragma unroll
    for (int r=0;r<4;r++){
      #pragma unroll
      for (int off=1; off<16; off<<=1)
        rowsum[r] += __shfl_xor(rowsum[r], off, 64);
      l_i[r] = l_i[r]*alpha[r] + rowsum[r];
    }
    #pragma unroll
    for (int t=0;t<4;t++)
      #pragma unroll
      for (int r=0;r<4;r++)
        oacc[t][r] *= alpha[r];

    // P: C-layout -> A-layout via per-wave LDS round trip (m120 pattern)
    #pragma unroll
    for (int t=0;t<4;t++){
      int col = t*16 + ln;
      int pc = col >> 3, jj = col & 7;
      #pragma unroll
      for (int r=0;r<4;r++)
        Pw[(pc*16 + quad*4 + r)*8 + jj] = f2bf(sacc[t][r]);
    }
    asm volatile("s_waitcnt lgkmcnt(0)" ::: "memory");

    // PV: contract over 64 keys (2 steps), vdim in 4 subtiles
    bh8 pf0 = *(const bh8*)(&Pw[((0*4+quad)*16 + ln)*8]);
    bh8 pf1 = *(const bh8*)(&Pw[((1*4+quad)*16 + ln)*8]);
    #pragma unroll
    for (int vt=0; vt<4; vt++){
      bh8 vf0 = *(const bh8*)(&Vt[((0*4+quad)*64 + vt*16 + ln)*8]);
      bh8 vf1 = *(const bh8*)(&Vt[((1*4+quad)*64 + vt*16 + ln)*8]);
      oacc[vt] = __builtin_amdgcn_mfma_f32_16x16x32_bf16(pf0, vf0, oacc[vt], 0,0,0);
      oacc[vt] = __builtin_amdgcn_mfma_f32_16x16x32_bf16(pf1, vf1, oacc[vt], 0,0,0);
    }
  }

  // epilogue: O = acc / l
  #pragma unroll
  for (int vt=0; vt<4; vt++)
    #pragma unroll
    for (int r=0;r<4;r++){
      float ov = oacc[vt][r] / l_i[r];
      O[(size_t)(b*S_ + q0w + quad*4 + r)*D_ + headoff + vt*16 + ln] = f2bf(ov);
    }
}

extern "C" void kernel_launch(void* const* d_in, const int* in_sizes, int n_in,
                              void* d_out, int out_size, void* d_ws, size_t ws_size,
                              hipStream_t stream){
  const float* q  = (const float*)d_in[0];
  const float* k  = (const float*)d_in[1];
  const float* v  = (const float*)d_in[2];
  const float* Wq = (const float*)d_in[3];
  const float* Wk = (const float*)d_in[4];
  const float* Wv = (const float*)d_in[5];
  const float* Wo = (const float*)d_in[6];
  // d_in[7] = causal mask, statically known -> ignored

  u16* ws  = (u16*)d_ws;
  u16* WqT = ws;
  u16* WkT = ws + (size_t)1*1024*1024;
  u16* WvT = ws + (size_t)2*1024*1024;
  u16* WoT = ws + (size_t)3*1024*1024;
  u16* Qp  = ws + (size_t)4*1024*1024;
  u16* Kp  = Qp + (size_t)M_*D_;
  u16* Vp  = Kp + (size_t)M_*D_;
  u16* Ao  = Qp;   // alias: attn consumes Q and overwrites it with O (safe, see attn_k)

  dim3 tb(32,8), tg(32,32);
  transpose_k<<<tg, tb, 0, stream>>>(Wq, WqT);
  transpose_k<<<tg, tb, 0, stream>>>(Wk, WkT);
  transpose_k<<<tg, tb, 0, stream>>>(Wv, WvT);
  transpose_k<<<tg, tb, 0, stream>>>(Wo, WoT);

  dim3 gg(D_/128, M_/128);   // (8, 64)
  gemm_bt<true , false><<<gg, 256, 0, stream>>>((const void*)q, WqT, (void*)Qp, D_, D_);
  gemm_bt<true , false><<<gg, 256, 0, stream>>>((const void*)k, WkT, (void*)Kp, D_, D_);
  gemm_bt<true , false><<<gg, 256, 0, stream>>>((const void*)v, WvT, (void*)Vp, D_, D_);

  attn_k<<<dim3(S_/64, B_*H_), 256, 0, stream>>>(Qp, Kp, Vp, Ao);

  // final projection: bf16 A, fp32 C straight into d_out (reference output dtype = float32)
  gemm_bt<false, true ><<<gg, 256, 0, stream>>>((const void*)Ao, WoT, d_out, D_, D_);
}

// Round 4
// 586.485 us; speedup vs baseline: 1.1851x; 1.1851x over previous
//
#include <hip/hip_runtime.h>
#include <hip/hip_bf16.h>
#include <stdint.h>

#define B_  4
#define S_  2048
#define D_  1024
#define H_  16
#define DK_ 64
#define M_  (B_*S_)   // 8192

typedef unsigned short u16;
using bh8  = __attribute__((ext_vector_type(8))) short;
using fx4  = __attribute__((ext_vector_type(4))) float;

__device__ __forceinline__ u16 f2bf(float f){
  union { float f; uint32_t u; } v; v.f = f;
  uint32_t r = v.u + 0x7FFFu + ((v.u >> 16) & 1u);
  return (u16)(r >> 16);
}

// async global->LDS, 16B per lane. LDS dest must be wave-uniform base + lane*16.
__device__ __forceinline__ void gl16(const void* g, void* l){
  __builtin_amdgcn_global_load_lds(
      (const __attribute__((address_space(1))) unsigned int*)g,
      (__attribute__((address_space(3))) unsigned int*)l, 16, 0, 0);
}

// ---------- transpose+convert 1024x1024: out_bf16[n][k] = in_f32[k][n] ----------
__global__ __launch_bounds__(256) void transpose_k(const float* __restrict__ in,
                                                   u16* __restrict__ out){
  __shared__ u16 tile[32][33];
  int tx = threadIdx.x, ty = threadIdx.y;
  int x0 = blockIdx.x*32, y0 = blockIdx.y*32;
  #pragma unroll
  for (int j=0;j<32;j+=8) tile[ty+j][tx] = f2bf(in[(size_t)(y0+ty+j)*D_ + x0+tx]);
  __syncthreads();
  #pragma unroll
  for (int j=0;j<32;j+=8) out[(size_t)(x0+ty+j)*D_ + y0+tx] = tile[tx][ty+j];
}

// ---------- fp32 -> bf16 flat convert (8 elems/thread) ----------
__global__ __launch_bounds__(256) void cvt_k(const float* __restrict__ in,
                                             u16* __restrict__ out, int n8){
  int i = blockIdx.x*256 + threadIdx.x;
  if (i >= n8) return;
  const float4* p = (const float4*)(in + (size_t)i*8);
  float4 a0 = p[0], a1 = p[1];
  u16 o[8];
  o[0]=f2bf(a0.x); o[1]=f2bf(a0.y); o[2]=f2bf(a0.z); o[3]=f2bf(a0.w);
  o[4]=f2bf(a1.x); o[5]=f2bf(a1.y); o[6]=f2bf(a1.z); o[7]=f2bf(a1.w);
  *(bh8*)(out + (size_t)i*8) = *(bh8*)o;
}

// ---------- per-head V transpose: VtG[(bh*64+vd)][token] = Vp[token][h*64+vd] ----------
__global__ __launch_bounds__(256) void vt_k(const u16* __restrict__ Vp,
                                            u16* __restrict__ VtG){
  int bh = blockIdx.y; int b = bh>>4, h = bh&15;
  int t0 = blockIdx.x*64;
  int vd = threadIdx.x & 63, g = threadIdx.x >> 6;
  #pragma unroll
  for (int j=0;j<2;j++){
    int tj = t0 + g*16 + j*8;
    u16 tmp[8];
    #pragma unroll
    for (int e=0;e<8;e++)
      tmp[e] = Vp[(size_t)(b*S_ + tj + e)*D_ + h*64 + vd];   // coalesced across vd-lanes
    *(bh8*)(&VtG[(size_t)(bh*64 + vd)*S_ + tj]) = *(bh8*)tmp;
  }
}

// ---------- C[M,N] = A[M,K] @ BT[N,K]^T, bf16 in, fp32 accum, bf16/fp32 out ----------
// m97 structure: 128x128 tile, 4 waves, 4x4 mfma_f32_16x16x32_bf16,
// global_load_lds dwordx4 staging into slot = kc*128 + r (lane-linear dest).
template<bool COUT32>
__global__ __launch_bounds__(256) void gemm_bt(const u16* __restrict__ A,
                                               const u16* __restrict__ BT,
                                               void* __restrict__ Cptr,
                                               int Kdim, int Ndim){
  __shared__ __align__(16) u16 Asl[128*32];
  __shared__ __align__(16) u16 Bsl[128*32];
  int tid  = threadIdx.x;
  int w    = tid >> 6, lane = tid & 63, quad = lane >> 4, ln = lane & 15;
  int waveM = w >> 1, waveN = w & 1;
  int rowBase = blockIdx.y*128, colBase = blockIdx.x*128;

  fx4 acc[4][4];
  #pragma unroll
  for (int i=0;i<4;i++)
    #pragma unroll
    for (int j=0;j<4;j++) acc[i][j] = (fx4){0.f,0.f,0.f,0.f};

  for (int k0 = 0; k0 < Kdim; k0 += 32){
    __syncthreads();
    #pragma unroll
    for (int i=0;i<2;i++){
      int slot = i*256 + tid;
      int kc = slot >> 7, r = slot & 127;
      gl16(&A [(size_t)(rowBase + r)*Kdim + k0 + kc*8], &Asl[slot*8]);
      gl16(&BT[(size_t)(colBase + r)*Kdim + k0 + kc*8], &Bsl[slot*8]);
    }
    __syncthreads();   // drains vmcnt(0) + barrier
    bh8 af[4], bf[4];
    #pragma unroll
    for (int t=0;t<4;t++){
      af[t] = *(const bh8*)(&Asl[(quad*128 + waveM*64 + t*16 + ln)*8]);
      bf[t] = *(const bh8*)(&Bsl[(quad*128 + waveN*64 + t*16 + ln)*8]);
    }
    #pragma unroll
    for (int i=0;i<4;i++)
      #pragma unroll
      for (int j=0;j<4;j++)
        acc[i][j] = __builtin_amdgcn_mfma_f32_16x16x32_bf16(af[i], bf[j], acc[i][j], 0, 0, 0);
  }

  // epilogue: C/D layout col = lane&15, row = quad*4 + reg  [m89/m91-verified]
  #pragma unroll
  for (int i=0;i<4;i++){
    int row0 = rowBase + waveM*64 + i*16 + quad*4;
    #pragma unroll
    for (int j=0;j<4;j++){
      int col = colBase + waveN*64 + j*16 + ln;
      #pragma unroll
      for (int r=0;r<4;r++){
        if (COUT32) ((float*)Cptr)[(size_t)(row0 + r)*Ndim + col] = acc[i][j][r];
        else        ((u16*)  Cptr)[(size_t)(row0 + r)*Ndim + col] = f2bf(acc[i][j][r]);
      }
    }
  }
}

// ---------- flash attention, causal ----------
// One block per (b,h, 64-row q tile); k-tile = 128. V pre-transposed (VtG).
// All LDS tiles use XOR-swizzled 16B chunk slots: chunk (row, c) lives at
// slot = row*CH + (c ^ (row & (CH-1))) -> conflict-free staging AND b128 reads.
// O aliases Q (disjoint per block; Q read into regs before first store).
__global__ __launch_bounds__(256) void attn_k(const u16* __restrict__ Q,
                                              const u16* __restrict__ Kp,
                                              const u16* __restrict__ VtG,
                                              u16* __restrict__ O){
  __shared__ __align__(16) u16 Kt[128*64];    // 128 keys x 64 dk, CH=8
  __shared__ __align__(16) u16 Vt[64*128];    // 64 vd  x 128 kpos, CH=16
  __shared__ __align__(16) u16 Pb[4*16*128];  // per wave: 16 q x 128 kpos, CH=16

  int qt = (int)gridDim.x - 1 - (int)blockIdx.x;   // big blocks first
  int bh = blockIdx.y; int b = bh>>4, h = bh&15;
  int tid = threadIdx.x;
  int w = tid >> 6, lane = tid & 63, quad = lane >> 4, ln = lane & 15;
  int q0w = qt*64 + w*16;
  size_t headoff = (size_t)h*DK_;

  // Q fragments (A-operand: m=lane&15, k=quad*8+j)
  bh8 qf0, qf1;
  {
    const u16* qp = Q + (size_t)(b*S_ + q0w + ln)*D_ + headoff + quad*8;
    qf0 = *(const bh8*)qp;
    qf1 = *(const bh8*)(qp + 32);
  }

  const float c1 = 0.125f * 1.44269504089f;   // 1/sqrt(64) * log2(e)
  float m_i[4], l_i[4];
  fx4 oacc[4];
  #pragma unroll
  for (int r=0;r<4;r++){ m_i[r] = -1e30f; l_i[r] = 0.f; }
  #pragma unroll
  for (int t=0;t<4;t++) oacc[t] = (fx4){0.f,0.f,0.f,0.f};

  u16* Pw = &Pb[w*16*128];
  int ntiles = (qt >> 1) + 1;                 // causal, 128-key tiles
  for (int kt=0; kt<ntiles; kt++){
    int k0 = kt*128;
    __syncthreads();
    // stage K: 1024 chunks, slot s -> (n = s>>3, kc = (s&7) ^ (n&7))
    #pragma unroll
    for (int i=0;i<4;i++){
      int s = i*256 + tid;
      int n = s >> 3, kc = (s & 7) ^ (n & 7);
      gl16(&Kp[(size_t)(b*S_ + k0 + n)*D_ + headoff + kc*8], &Kt[s*8]);
    }
    // stage V^T: 1024 chunks, slot s -> (vd = s>>4, c = (s&15) ^ (vd&15))
    #pragma unroll
    for (int i=0;i<4;i++){
      int s = i*256 + tid;
      int vd = s >> 4, c = (s & 15) ^ (vd & 15);
      gl16(&VtG[(size_t)(bh*64 + vd)*S_ + k0 + c*8], &Vt[s*8]);
    }
    __syncthreads();   // drains vmcnt(0) + barrier

    // QK^T: per wave 16q x 128k = 8 accs, 2 dk-steps each
    fx4 sacc[8];
    #pragma unroll
    for (int t=0;t<8;t++){
      int n = t*16 + ln;
      bh8 kf0 = *(const bh8*)(&Kt[(n*8 + ((0*4+quad) ^ (ln&7)))*8]);
      bh8 kf1 = *(const bh8*)(&Kt[(n*8 + ((1*4+quad) ^ (ln&7)))*8]);
      fx4 z = (fx4){0.f,0.f,0.f,0.f};
      z = __builtin_amdgcn_mfma_f32_16x16x32_bf16(qf0, kf0, z, 0,0,0);
      z = __builtin_amdgcn_mfma_f32_16x16x32_bf16(qf1, kf1, z, 0,0,0);
      sacc[t] = z;
    }

    // scale(log2-domain) + causal mask; online softmax (rows = quad*4+reg)
    float rowmax[4] = {-1e30f,-1e30f,-1e30f,-1e30f};
    #pragma unroll
    for (int t=0;t<8;t++){
      int kg = k0 + t*16 + ln;
      #pragma unroll
      for (int r=0;r<4;r++){
        int qg = q0w + quad*4 + r;
        float sv = sacc[t][r]*c1;
        sv = (kg <= qg) ? sv : -1e30f;
        sacc[t][r] = sv;
        rowmax[r] = fmaxf(rowmax[r], sv);
      }
    }
    #pragma unroll
    for (int r=0;r<4;r++)
      #pragma unroll
      for (int off=1; off<16; off<<=1)
        rowmax[r] = fmaxf(rowmax[r], __shfl_xor(rowmax[r], off, 64));

    float alpha[4], rowsum[4];
    #pragma unroll
    for (int r=0;r<4;r++){
      float mn = fmaxf(m_i[r], rowmax[r]);
      alpha[r] = exp2f(m_i[r] - mn);
      m_i[r] = mn;
      rowsum[r] = 0.f;
    }
    #pragma unroll
    for (int t=0;t<8;t++)
      #pragma unroll
      for (int r=0;r<4;r++){
        float p = exp2f(sacc[t][r] - m_i[r]);
        sacc[t][r] = p;
        rowsum[r] += p;
      }
    #pragma unroll
    for (int r=0;r<4;r++){
      #pragma unroll
      for (int off=1; off<16; off<<=1)
        rowsum[r] += __shfl_xor(rowsum[r], off, 64);
      l_i[r] = l_i[r]*alpha[r] + rowsum[r];
    }
    #pragma unroll
    for (int t=0;t<4;t++)
      #pragma unroll
      for (int r=0;r<4;r++)
        oacc[t][r] *= alpha[r];

    // P: C-layout -> A-layout via per-wave LDS, swizzled slots (CH=16)
    #pragma unroll
    for (int t=0;t<8;t++){
      int col = t*16 + ln;
      int c = col >> 3, jj = col & 7;
      #pragma unroll
      for (int r=0;r<4;r++){
        int m = quad*4 + r;
        Pw[(m*16 + (c ^ m))*8 + jj] = f2bf(sacc[t][r]);
      }
    }
    asm volatile("s_waitcnt lgkmcnt(0)" ::: "memory");  // wave-local LDS ordering

    // PV: contract 128 keys in 4 steps, vdim in 4 subtiles
    #pragma unroll
    for (int s3=0; s3<4; s3++){
      int c = s3*4 + quad;
      bh8 pf = *(const bh8*)(&Pw[(ln*16 + (c ^ ln))*8]);
      #pragma unroll
      for (int vt=0; vt<4; vt++){
        int vd = vt*16 + ln;
        bh8 vf = *(const bh8*)(&Vt[(vd*16 + (c ^ ln))*8]);
        oacc[vt] = __builtin_amdgcn_mfma_f32_16x16x32_bf16(pf, vf, oacc[vt], 0,0,0);
      }
    }
  }

  // epilogue: O = acc / l
  #pragma unroll
  for (int vt=0; vt<4; vt++)
    #pragma unroll
    for (int r=0;r<4;r++){
      float ov = oacc[vt][r] / l_i[r];
      O[(size_t)(b*S_ + q0w + quad*4 + r)*D_ + headoff + vt*16 + ln] = f2bf(ov);
    }
}

extern "C" void kernel_launch(void* const* d_in, const int* in_sizes, int n_in,
                              void* d_out, int out_size, void* d_ws, size_t ws_size,
                              hipStream_t stream){
  const float* q  = (const float*)d_in[0];
  const float* k  = (const float*)d_in[1];
  const float* v  = (const float*)d_in[2];
  const float* Wq = (const float*)d_in[3];
  const float* Wk = (const float*)d_in[4];
  const float* Wv = (const float*)d_in[5];
  const float* Wo = (const float*)d_in[6];
  // d_in[7] = causal mask, statically known -> ignored

  const size_t MD = (size_t)M_*D_;        // 8.39M elements
  u16* ws  = (u16*)d_ws;
  u16* WqT = ws;
  u16* WkT = ws + (size_t)1*1024*1024;
  u16* WvT = ws + (size_t)2*1024*1024;
  u16* WoT = ws + (size_t)3*1024*1024;
  u16* xb  = ws + (size_t)4*1024*1024;    // reused: bf16 input staging, then VtG
  u16* Qp  = xb + MD;
  u16* Kp  = Qp + MD;
  u16* Vp  = Kp + MD;
  u16* Ao  = Qp;   // attn writes O over Q (safe, see attn_k)

  dim3 tb(32,8), tg(32,32);
  transpose_k<<<tg, tb, 0, stream>>>(Wq, WqT);
  transpose_k<<<tg, tb, 0, stream>>>(Wk, WkT);
  transpose_k<<<tg, tb, 0, stream>>>(Wv, WvT);
  transpose_k<<<tg, tb, 0, stream>>>(Wo, WoT);

  const int n8 = (int)(MD/8);
  dim3 gg(D_/128, M_/128);   // (8, 64)

  cvt_k<<<(n8+255)/256, 256, 0, stream>>>(q, xb, n8);
  gemm_bt<false><<<gg, 256, 0, stream>>>(xb, WqT, (void*)Qp, D_, D_);
  cvt_k<<<(n8+255)/256, 256, 0, stream>>>(k, xb, n8);
  gemm_bt<false><<<gg, 256, 0, stream>>>(xb, WkT, (void*)Kp, D_, D_);
  cvt_k<<<(n8+255)/256, 256, 0, stream>>>(v, xb, n8);
  gemm_bt<false><<<gg, 256, 0, stream>>>(xb, WvT, (void*)Vp, D_, D_);

  vt_k<<<dim3(S_/64, B_*H_), 256, 0, stream>>>(Vp, xb);   // xb = VtG now

  attn_k<<<dim3(S_/64, B_*H_), 256, 0, stream>>>(Qp, Kp, xb, Ao);

  // final projection: fp32 C straight into d_out
  gemm_bt<true ><<<gg, 256, 0, stream>>>(Ao, WoT, d_out, D_, D_);
}